// Round 1
// baseline (623.907 us; speedup 1.0000x reference)
//
#include <hip/hip_runtime.h>

#define B_ 4
#define T_ 2048
#define D_ 128
#define H_ 8
#define DK_ 16

typedef __attribute__((ext_vector_type(8))) short short8;
typedef __attribute__((ext_vector_type(4))) float floatx4;

__device__ __forceinline__ short f2bf(float x) {
    unsigned u = __builtin_bit_cast(unsigned, x);
    u += 0x7FFFu + ((u >> 16) & 1u);   // RNE
    return (short)(u >> 16);
}

__device__ __forceinline__ unsigned cvt_pk_bf16(float lo, float hi) {
    unsigned r;
    asm("v_cvt_pk_bf16_f32 %0, %1, %2" : "=v"(r) : "v"(lo), "v"(hi));
    return r;
}

// ---------------------------------------------------------------------------
// Kernel 1: QKV projections.  grid = 3*512 blocks, 64 threads.
// Q stored bf16 [bh][t][16] pre-scaled by 0.25; K bf16 [bh][t][16];
// V stored transposed bf16 [bh][16][t].
// ---------------------------------------------------------------------------
__global__ __launch_bounds__(64) void qkv_kernel(
    const float* __restrict__ q_in, const float* __restrict__ k_in,
    const float* __restrict__ v_in,
    const float* __restrict__ Wq, const float* __restrict__ bq,
    const float* __restrict__ Wk, const float* __restrict__ bk,
    const float* __restrict__ Wv, const float* __restrict__ bv,
    short* __restrict__ q_ws, short* __restrict__ k_ws, short* __restrict__ vt_ws)
{
    int mat = blockIdx.x >> 9;          // 0=Q 1=K 2=V
    int rb  = blockIdx.x & 511;
    int row0 = rb * 16;                 // global row in [0, 8192)
    int b  = row0 >> 11;
    int t0 = row0 & (T_ - 1);

    const float* X    = (mat == 0) ? q_in : (mat == 1) ? k_in : v_in;
    const float* W    = (mat == 0) ? Wq   : (mat == 1) ? Wk   : Wv;
    const float* bias = (mat == 0) ? bq   : (mat == 1) ? bk   : bv;

    __shared__ float xt[16][128];
    int tid = threadIdx.x;
    #pragma unroll
    for (int i = 0; i < 8; ++i) {
        int idx = tid + i * 64;         // 512 float4 chunks
        int r = idx >> 5, c4 = idx & 31;
        *(float4*)&xt[r][c4 * 4] =
            *(const float4*)&X[(size_t)(row0 + r) * 128 + c4 * 4];
    }
    __syncthreads();

    int c0 = tid, c1 = tid + 64;
    float accA[16], accB[16];
    float b0 = bias[c0], b1 = bias[c1];
    #pragma unroll
    for (int r = 0; r < 16; ++r) { accA[r] = b0; accB[r] = b1; }

    for (int d4 = 0; d4 < 32; ++d4) {
        float w0[4], w1[4];
        #pragma unroll
        for (int j = 0; j < 4; ++j) {
            w0[j] = W[(d4 * 4 + j) * 128 + c0];
            w1[j] = W[(d4 * 4 + j) * 128 + c1];
        }
        #pragma unroll
        for (int r = 0; r < 16; ++r) {
            float4 xv = *(const float4*)&xt[r][d4 * 4];
            accA[r] += xv.x * w0[0] + xv.y * w0[1] + xv.z * w0[2] + xv.w * w0[3];
            accB[r] += xv.x * w1[0] + xv.y * w1[1] + xv.z * w1[2] + xv.w * w1[3];
        }
    }

    int hA = c0 >> 4, dA = c0 & 15;
    int hB = c1 >> 4, dB = c1 & 15;
    #pragma unroll
    for (int r = 0; r < 16; ++r) {
        int t = t0 + r;
        float vA = accA[r], vB = accB[r];
        if (mat == 0) { vA *= 0.25f; vB *= 0.25f; }   // fold 1/sqrt(dk) into Q
        if (mat == 2) {
            vt_ws[((size_t)(b * H_ + hA) * DK_ + dA) * T_ + t] = f2bf(vA);
            vt_ws[((size_t)(b * H_ + hB) * DK_ + dB) * T_ + t] = f2bf(vB);
        } else {
            short* dst = (mat == 0) ? q_ws : k_ws;
            dst[((size_t)(b * H_ + hA) * T_ + t) * DK_ + dA] = f2bf(vA);
            dst[((size_t)(b * H_ + hB) * T_ + t) * DK_ + dB] = f2bf(vB);
        }
    }
}

// ---------------------------------------------------------------------------
// Kernel 2: attention.  grid = 32 bh * 8 qchunks = 256 blocks, 512 threads.
// Swapped-operand QK^T:  S^T = mfma(K_frag, Q_frag)  ->  lane l15 owns one
// q-row, register quad owns 4 consecutive k-cols.  attn written as float4
// (16 B/lane); P staged to per-wave LDS tile via cvt_pk_bf16 + ds_write_b64;
// PV MFMA reads the same verified A-frag layout as before.
// ---------------------------------------------------------------------------
__global__ __launch_bounds__(512) void attn_kernel(
    const short* __restrict__ q_ws, const short* __restrict__ k_ws,
    const short* __restrict__ vt_ws,
    float* __restrict__ attn, float* __restrict__ ctx_ws)
{
    __shared__ __align__(16) short klds[T_ * DK_];          // 65536 B
    __shared__ __align__(16) short vtlds[DK_ * (T_ + 8)];   // 65792 B
    __shared__ __align__(16) short tblds[8 * 16 * 40];      // 10240 B (per-wave 16x32 tile, pitch 80 B)

    int tid = threadIdx.x;
    int bh = blockIdx.x >> 3;
    int qc = blockIdx.x & 7;
    int b = bh >> 3, h = bh & 7;

    const short* kbase  = k_ws  + (size_t)bh * T_ * DK_;
    const short* vtbase = vt_ws + (size_t)bh * DK_ * T_;

    #pragma unroll
    for (int i = 0; i < 8; ++i) {             // stage K: 4096 16B chunks
        int idx = tid + i * 512;
        *(short8*)&klds[idx * 8] = *(const short8*)&kbase[idx * 8];
    }
    #pragma unroll
    for (int i = 0; i < 8; ++i) {             // stage V^T with +8 row pad
        int idx = tid + i * 512;
        int d = idx >> 8, off = idx & 255;
        *(short8*)&vtlds[d * (T_ + 8) + off * 8] =
            *(const short8*)&vtbase[d * T_ + off * 8];
    }
    __syncthreads();

    int wid = tid >> 6, lane = tid & 63;
    int l15 = lane & 15, quad = lane >> 4;
    int half8 = (quad & 1) * 8;               // which 8 of the padded K=32
    short8 z8 = {0, 0, 0, 0, 0, 0, 0, 0};

    float* attn_bh = attn + (size_t)bh * T_ * T_;

    for (int tt = 0; tt < 2; ++tt) {
        int qrow0 = qc * 256 + tt * 128 + wid * 16;

        // Q as B-frag: B[n=l15][k=quad*8+j]; quads 2,3 are the dk pad -> zero
        short8 bq = *(const short8*)
            &q_ws[((size_t)bh * T_ + qrow0 + l15) * DK_ + half8];
        if (quad >= 2) bq = z8;

        // ---- pass 1: per-lane row sums of exp(s) over this lane's q-row ----
        float lsum = 0.f;
        for (int tk0 = 0; tk0 < T_; tk0 += 32) {
            short8 ak0 = *(const short8*)&klds[(tk0 + l15) * DK_ + half8];
            short8 ak1 = *(const short8*)&klds[(tk0 + 16 + l15) * DK_ + half8];
            if (quad >= 2) { ak0 = z8; ak1 = z8; }
            floatx4 s0 = __builtin_amdgcn_mfma_f32_16x16x32_bf16(
                ak0, bq, (floatx4){0.f, 0.f, 0.f, 0.f}, 0, 0, 0);
            floatx4 s1 = __builtin_amdgcn_mfma_f32_16x16x32_bf16(
                ak1, bq, (floatx4){0.f, 0.f, 0.f, 0.f}, 0, 0, 0);
            #pragma unroll
            for (int r = 0; r < 4; ++r)
                lsum += __expf(s0[r]) + __expf(s1[r]);
        }
        lsum += __shfl_xor(lsum, 16);         // reduce across the 4 quads
        lsum += __shfl_xor(lsum, 32);
        float inv = 1.0f / lsum;

        // ---- pass 2: recompute S^T, write attn (float4), accumulate P V ----
        short* tb = &tblds[wid * 16 * 40];
        floatx4 ctx = {0.f, 0.f, 0.f, 0.f};
        float* ap = attn_bh + (size_t)(qrow0 + l15) * T_;

        for (int tk0 = 0; tk0 < T_; tk0 += 32) {
            short8 ak0 = *(const short8*)&klds[(tk0 + l15) * DK_ + half8];
            short8 ak1 = *(const short8*)&klds[(tk0 + 16 + l15) * DK_ + half8];
            if (quad >= 2) { ak0 = z8; ak1 = z8; }
            floatx4 s0 = __builtin_amdgcn_mfma_f32_16x16x32_bf16(
                ak0, bq, (floatx4){0.f, 0.f, 0.f, 0.f}, 0, 0, 0);
            floatx4 s1 = __builtin_amdgcn_mfma_f32_16x16x32_bf16(
                ak1, bq, (floatx4){0.f, 0.f, 0.f, 0.f}, 0, 0, 0);

            float p0[4], p1[4];
            #pragma unroll
            for (int r = 0; r < 4; ++r) {
                p0[r] = __expf(s0[r]) * inv;  // P[q=l15][tk0 + quad*4 + r]
                p1[r] = __expf(s1[r]) * inv;  // P[q=l15][tk0 + 16 + quad*4 + r]
            }
            *(float4*)(ap + tk0 + quad * 4) =
                make_float4(p0[0], p0[1], p0[2], p0[3]);
            *(float4*)(ap + tk0 + 16 + quad * 4) =
                make_float4(p1[0], p1[1], p1[2], p1[3]);

            // stage P as bf16 into per-wave tile: row = q (l15), col = k
            unsigned u0 = cvt_pk_bf16(p0[0], p0[1]);
            unsigned u1 = cvt_pk_bf16(p0[2], p0[3]);
            unsigned u2 = cvt_pk_bf16(p1[0], p1[1]);
            unsigned u3 = cvt_pk_bf16(p1[2], p1[3]);
            uint2 w01 = {u0, u1}, w23 = {u2, u3};
            *(uint2*)&tb[l15 * 40 + quad * 4]      = w01;   // k = 4q .. 4q+3
            *(uint2*)&tb[l15 * 40 + 16 + quad * 4] = w23;   // k = 16+4q ..

            short8 pa = *(const short8*)&tb[l15 * 40 + quad * 8];            // P A-frag
            short8 vb = *(const short8*)&vtlds[l15 * (T_ + 8) + tk0 + quad * 8]; // V B-frag
            ctx = __builtin_amdgcn_mfma_f32_16x16x32_bf16(pa, vb, ctx, 0, 0, 0);
        }
        #pragma unroll
        for (int r = 0; r < 4; ++r)
            ctx_ws[((size_t)b * T_ + qrow0 + quad * 4 + r) * D_ + h * DK_ + l15] =
                ctx[r];
    }
}

// ---------------------------------------------------------------------------
// Kernel 3: out-proj + residual + LayerNorm.  grid = 512 blocks, 256 threads;
// one wave handles 4 rows, lane owns cols (lane, lane+64).
// ---------------------------------------------------------------------------
__global__ __launch_bounds__(256) void outln_kernel(
    const float* __restrict__ ctx_ws, const float* __restrict__ Wo,
    const float* __restrict__ bo, const float* __restrict__ q_in,
    const float* __restrict__ gamma, const float* __restrict__ beta,
    float* __restrict__ out)
{
    __shared__ float xrow[4][4][128];
    int tid = threadIdx.x, wid = tid >> 6, lane = tid & 63;
    int row0 = blockIdx.x * 16 + wid * 4;

    #pragma unroll
    for (int r = 0; r < 4; ++r) {
        xrow[wid][r][lane]      = ctx_ws[(size_t)(row0 + r) * 128 + lane];
        xrow[wid][r][lane + 64] = ctx_ws[(size_t)(row0 + r) * 128 + lane + 64];
    }

    float acc0[4], acc1[4];
    float bb0 = bo[lane], bb1 = bo[lane + 64];
    #pragma unroll
    for (int r = 0; r < 4; ++r) { acc0[r] = bb0; acc1[r] = bb1; }

    for (int d4 = 0; d4 < 32; ++d4) {
        float w0[4], w1[4];
        #pragma unroll
        for (int j = 0; j < 4; ++j) {
            w0[j] = Wo[(d4 * 4 + j) * 128 + lane];
            w1[j] = Wo[(d4 * 4 + j) * 128 + lane + 64];
        }
        #pragma unroll
        for (int r = 0; r < 4; ++r) {
            float4 xv = *(const float4*)&xrow[wid][r][d4 * 4];
            acc0[r] += xv.x * w0[0] + xv.y * w0[1] + xv.z * w0[2] + xv.w * w0[3];
            acc1[r] += xv.x * w1[0] + xv.y * w1[1] + xv.z * w1[2] + xv.w * w1[3];
        }
    }

    float g0 = gamma[lane], g1 = gamma[lane + 64];
    float be0 = beta[lane], be1 = beta[lane + 64];
    #pragma unroll
    for (int r = 0; r < 4; ++r) {
        size_t row = row0 + r;
        float x0 = acc0[r] + q_in[row * 128 + lane];
        float x1 = acc1[r] + q_in[row * 128 + lane + 64];
        float s = x0 + x1, s2 = x0 * x0 + x1 * x1;
        #pragma unroll
        for (int off = 1; off < 64; off <<= 1) {
            s  += __shfl_xor(s, off);
            s2 += __shfl_xor(s2, off);
        }
        float mean = s * (1.0f / 128.0f);
        float var  = s2 * (1.0f / 128.0f) - mean * mean;
        float rstd = rsqrtf(var + 1e-5f);
        out[row * 128 + lane]      = (x0 - mean) * rstd * g0 + be0;
        out[row * 128 + lane + 64] = (x1 - mean) * rstd * g1 + be1;
    }
}

// ---------------------------------------------------------------------------
extern "C" void kernel_launch(void* const* d_in, const int* in_sizes, int n_in,
                              void* d_out, int out_size, void* d_ws, size_t ws_size,
                              hipStream_t stream)
{
    const float* queries = (const float*)d_in[0];
    const float* keys    = (const float*)d_in[1];
    const float* values  = (const float*)d_in[2];
    const float* Wq = (const float*)d_in[3];  const float* bq = (const float*)d_in[4];
    const float* Wk = (const float*)d_in[5];  const float* bk = (const float*)d_in[6];
    const float* Wv = (const float*)d_in[7];  const float* bv = (const float*)d_in[8];
    const float* Wo = (const float*)d_in[9];  const float* bo = (const float*)d_in[10];
    const float* gamma = (const float*)d_in[11];
    const float* beta  = (const float*)d_in[12];

    // workspace layout: Q bf16 2MB | K bf16 2MB | V^T bf16 2MB | ctx f32 4MB
    short* q_ws  = (short*)d_ws;
    short* k_ws  = q_ws  + (1 << 20);
    short* vt_ws = k_ws  + (1 << 20);
    float* ctx_ws = (float*)(vt_ws + (1 << 20));

    float* out  = (float*)d_out;
    float* attn = out + (size_t)B_ * T_ * D_;

    qkv_kernel<<<dim3(3 * 512), dim3(64), 0, stream>>>(
        queries, keys, values, Wq, bq, Wk, bk, Wv, bv, q_ws, k_ws, vt_ws);
    attn_kernel<<<dim3(256), dim3(512), 0, stream>>>(
        q_ws, k_ws, vt_ws, attn, ctx_ws);
    outln_kernel<<<dim3(512), dim3(256), 0, stream>>>(
        ctx_ws, Wo, bo, queries, gamma, beta, out);
}